// Round 7
// baseline (253.863 us; speedup 1.0000x reference)
//
#include <hip/hip_runtime.h>

// DeepAttention: h = tanh([attn@ctx, x] @ Wout^T-ish), attn = softmax(mask(w . relu(ctx@W^T)))
// R7: k_logits v4 — direct HBM->register A-fragments with REGISTER DOUBLE-BUFFER prefetch
// (rgA/rgB), no loop barriers, W fragment-packed in LDS. Grid (2,B)=256 blocks = 1/CU.
// k_splitW+k_w merged into k_prep; k_detect shrunk.

#define BB 128
#define SS 8192
#define DD 128
#define WCH 16             // S-chunks for the weighted gather
#define WLEN (SS / WCH)    // 512 positions per gather block

typedef float f32x4_t __attribute__((ext_vector_type(4)));
typedef short bf16x8_t __attribute__((ext_vector_type(8)));
typedef unsigned short u16x8_t __attribute__((ext_vector_type(8)));
typedef unsigned int u32x4_t __attribute__((ext_vector_type(4)));

__device__ __forceinline__ unsigned short f2bf(float x) {
  unsigned u = __builtin_bit_cast(unsigned, x);
  unsigned r = (u + 0x7FFFu + ((u >> 16) & 1u)) >> 16;
  return (unsigned short)r;
}
__device__ __forceinline__ float bf2f(unsigned short h) {
  unsigned u = ((unsigned)h) << 16;
  return __builtin_bit_cast(float, u);
}
// hw pack: low16 = bf16(a), high16 = bf16(b)  (RNE)
__device__ __forceinline__ unsigned cvtpk(float a, float b) {
  unsigned r;
  asm("v_cvt_pk_bf16_f32 %0, %1, %2" : "=v"(r) : "v"(a), "v"(b));
  return r;
}

// ---- K0: detect mask storage format (0 = int32, 1 = uint8, 2 = float32) ----
// Scans first 256 KB (safe under all interpretations: min buffer = 1 MB as uint8).
__global__ void k_detect(const unsigned int* __restrict__ mw, unsigned int* __restrict__ flag) {
  int i = blockIdx.x * 256 + threadIdx.x;   // 256 blocks -> 65536 words = 256 KB
  unsigned v = mw[i];
  unsigned f = 0;
  if (v == 0x3F800000u) f = 2u;             // f32 1.0 pattern
  else if (v > 1u) f = 1u;                  // packed uint8 bools
  if (f) atomicOr(flag, f);
}

// ---- K1: merged prep. grid(128) x 128 thr.
// (a) W bf16 hi/lo split: element i = b*128+tid (16384 total)
// (b) w[b,e] = relu(x@W^T)[b,e] * V[e], fp32 exact
__global__ void k_prep(const float* __restrict__ inp, const float* __restrict__ Wg,
                       const float* __restrict__ Vg, unsigned short* __restrict__ Whi,
                       unsigned short* __restrict__ Wlo, float* __restrict__ wv) {
  const int b = blockIdx.x, tid = threadIdx.x;
  {
    int i = b * DD + tid;
    float x = Wg[i];
    unsigned short h = f2bf(x);
    Whi[i] = h;
    Wlo[i] = f2bf(x - bf2f(h));
  }
  __shared__ float xin[DD];
  xin[tid] = inp[b * DD + tid];
  __syncthreads();
  const float* wr = Wg + tid * DD;
  float s = 0.f;
#pragma unroll 8
  for (int d = 0; d < DD; ++d) s += xin[d] * wr[d];
  wv[b * DD + tid] = fmaxf(s, 0.f) * Vg[tid];
}

// ---- K2 v4: logits[b,s] = sum_e w[b,e]*relu(sum_d ctx[b,s,d]*W[e,d]) ----
// Register double-buffer: while computing rgA's 32 rows, rgB's 16KB is in flight.
// No barriers in the main loop. grid (2, BB) = 256 blocks, 512 thr, 1 block/CU.
__launch_bounds__(512, 2)
__global__ void k_logits(const float* __restrict__ ctx, const unsigned short* __restrict__ Whi,
                         const unsigned short* __restrict__ Wlo, const float* __restrict__ wv,
                         float* __restrict__ logits) {
  __shared__ unsigned short WPKH[16384];     // 32 KB: W-hi, fragment-packed
  __shared__ unsigned short WPKL[16384];     // 32 KB: W-lo
  __shared__ float wl[DD];

  const int tid = threadIdx.x;
  const int b = blockIdx.y;
  const int slice = blockIdx.x;              // 0..1, 4096 rows each

  const int wave = tid >> 6;
  const int lane = tid & 63;
  const int lr = lane & 15;
  const int lg = lane >> 4;

  // wave owns 512 contiguous rows: 16 groups of 32 rows (2 row-tiles of 16)
  const long rowb0 = (long)b * SS + (long)slice * 4096 + (long)wave * 512;

  f32x4_t rgA[16], rgB[16];

  auto issue = [&](f32x4_t (&rg)[16], long grow) {
#pragma unroll
    for (int rt = 0; rt < 2; ++rt) {
      const float* rp = ctx + (grow + rt * 16 + lr) * (long)DD + lg * 8;
#pragma unroll
      for (int ks = 0; ks < 4; ++ks) {
        rg[rt * 8 + ks * 2]     = *(const f32x4_t*)(rp + ks * 32);
        rg[rt * 8 + ks * 2 + 1] = *(const f32x4_t*)(rp + ks * 32 + 4);
      }
    }
  };

  issue(rgA, rowb0);                          // group-0 loads fly under W staging

  // Stage W hi/lo into packed-fragment layout. Packed unit p (16B) = frag p>>6, lane p&63.
#pragma unroll
  for (int jj = 0; jj < 4; ++jj) {
    int p = tid + jj * 512;                   // 2048 units per array
    int frag = p >> 6;                        // et*4 + ks
    int li = p & 63;
    int et = frag >> 2, ks = frag & 3;
    int lg2 = li >> 4, lr2 = li & 15;
    int src = (et * 16 + lr2) * DD + ks * 32 + lg2 * 8;
    *(u16x8_t*)(&WPKH[p * 8]) = *(const u16x8_t*)(&Whi[src]);
    *(u16x8_t*)(&WPKL[p * 8]) = *(const u16x8_t*)(&Wlo[src]);
  }
  if (tid < DD) wl[tid] = wv[b * DD + tid];
  __syncthreads();

  float wfreg[8];
#pragma unroll
  for (int et = 0; et < 8; ++et) wfreg[et] = wl[et * 16 + lr];

  auto compute = [&](const f32x4_t (&rg)[16], long grow) {
    // convert f32 -> bf16 fragments in-register
    bf16x8_t a[2][4];
#pragma unroll
    for (int rt = 0; rt < 2; ++rt) {
#pragma unroll
      for (int ks = 0; ks < 4; ++ks) {
        f32x4_t x0 = rg[rt * 8 + ks * 2];
        f32x4_t x1 = rg[rt * 8 + ks * 2 + 1];
        u32x4_t hh;
        hh[0] = cvtpk(x0[0], x0[1]);
        hh[1] = cvtpk(x0[2], x0[3]);
        hh[2] = cvtpk(x1[0], x1[1]);
        hh[3] = cvtpk(x1[2], x1[3]);
        a[rt][ks] = __builtin_bit_cast(bf16x8_t, hh);
      }
    }
    float part[2][4] = {{0.f, 0.f, 0.f, 0.f}, {0.f, 0.f, 0.f, 0.f}};
#pragma unroll
    for (int et = 0; et < 8; ++et) {
      bf16x8_t bh[4], bl[4];
#pragma unroll
      for (int ks = 0; ks < 4; ++ks) {
        const int pidx = ((((et << 2) | ks) << 6) | lane) << 3;
        bh[ks] = *(const bf16x8_t*)(&WPKH[pidx]);
        bl[ks] = *(const bf16x8_t*)(&WPKL[pidx]);
      }
      const float wf = wfreg[et];
#pragma unroll
      for (int rt = 0; rt < 2; ++rt) {
        f32x4_t v1 = {0.f, 0.f, 0.f, 0.f};
        f32x4_t v2 = v1;
#pragma unroll
        for (int ks = 0; ks < 4; ++ks) {
          v1 = __builtin_amdgcn_mfma_f32_16x16x32_bf16(a[rt][ks], bh[ks], v1, 0, 0, 0);
          v2 = __builtin_amdgcn_mfma_f32_16x16x32_bf16(a[rt][ks], bl[ks], v2, 0, 0, 0);
        }
#pragma unroll
        for (int i = 0; i < 4; ++i)
          part[rt][i] += wf * fmaxf(v1[i] + v2[i], 0.f);
      }
    }
    // reduce over e (16 lanes share a row), store
#pragma unroll
    for (int rt = 0; rt < 2; ++rt) {
#pragma unroll
      for (int m = 1; m < 16; m <<= 1) {
        part[rt][0] += __shfl_xor(part[rt][0], m, 64);
        part[rt][1] += __shfl_xor(part[rt][1], m, 64);
        part[rt][2] += __shfl_xor(part[rt][2], m, 64);
        part[rt][3] += __shfl_xor(part[rt][3], m, 64);
      }
    }
    if (lr == 0) {                            // C row = 4*lg + i
      long so = grow + lg * 4;
      logits[so + 0]  = part[0][0];
      logits[so + 1]  = part[0][1];
      logits[so + 2]  = part[0][2];
      logits[so + 3]  = part[0][3];
      logits[so + 16] = part[1][0];
      logits[so + 17] = part[1][1];
      logits[so + 18] = part[1][2];
      logits[so + 19] = part[1][3];
    }
  };

#pragma unroll 1
  for (int it = 0; it < 8; ++it) {            // 2 groups per iteration = 16 groups
    const long gA = rowb0 + (long)it * 64;
    const long gB = gA + 32;
    issue(rgB, gB);
    compute(rgA, gA);
    if (it < 7) issue(rgA, gA + 64);
    compute(rgB, gB);
  }
}

// ---- K3: masked softmax over S per batch, in place over logits ----
__global__ void k_softmax(const float* __restrict__ logits, const void* __restrict__ mask,
                          const unsigned int* __restrict__ flag, float* __restrict__ attn) {
  const int b = blockIdx.x;
  const int tid = threadIdx.x;                  // 256
  __shared__ float buf[SS];                     // 32 KiB
  __shared__ float red[4];
  const unsigned mode = *flag;
  const long off = (long)b * SS;
  float mx = -3.4e38f;
  for (int i = tid; i < SS; i += 256) {
    float v = logits[off + i];
    bool m;
    if (mode == 0)      m = ((const int*)mask)[off + i] != 0;
    else if (mode == 1) m = ((const unsigned char*)mask)[off + i] != 0;
    else                m = ((const float*)mask)[off + i] != 0.f;
    if (m) v = -1e12f;
    buf[i] = v;
    mx = fmaxf(mx, v);
  }
#pragma unroll
  for (int m2 = 32; m2; m2 >>= 1) mx = fmaxf(mx, __shfl_xor(mx, m2, 64));
  if ((tid & 63) == 0) red[tid >> 6] = mx;
  __syncthreads();
  mx = fmaxf(fmaxf(red[0], red[1]), fmaxf(red[2], red[3]));
  float sum = 0.f;
  for (int i = tid; i < SS; i += 256) {
    float e = expf(buf[i] - mx);
    buf[i] = e;
    sum += e;
  }
#pragma unroll
  for (int m2 = 32; m2; m2 >>= 1) sum += __shfl_xor(sum, m2, 64);
  __syncthreads();
  if ((tid & 63) == 0) red[tid >> 6] = sum;
  __syncthreads();
  float inv = 1.f / (red[0] + red[1] + red[2] + red[3]);
  for (int i = tid; i < SS; i += 256) attn[off + i] = buf[i] * inv;
}

// ---- K4: partial weighted sums. grid (B, WCH), 256 thr. wpart[b][c][d] ----
// f32x4 per lane: 32 lanes cover a row; 8 groups x 2-deep unroll = 16 rows in flight.
__global__ void k_wpartial(const float* __restrict__ attn, const float* __restrict__ ctx,
                           float* __restrict__ wpart) {
  const int b = blockIdx.x, c = blockIdx.y;
  const int tid = threadIdx.x;                  // 256
  __shared__ unsigned short slist[WLEN];
  __shared__ float plist[WLEN];
  __shared__ f32x4_t part[256];                 // 4 KB
  __shared__ unsigned cnt;
  if (tid == 0) cnt = 0;
  __syncthreads();
  const long off = (long)b * SS + (long)c * WLEN;
  for (int i = tid; i < WLEN; i += 256) {
    float p = attn[off + i];
    if (p > 1e-8f) {                            // skipped mass <= 8192*1e-8*|ctx| ~ 5e-4
      unsigned k = atomicAdd(&cnt, 1u);
      slist[k] = (unsigned short)i;
      plist[k] = p;
    }
  }
  __syncthreads();
  const int n = (int)cnt;
  const int c4 = (tid & 31) * 4;
  const int g = tid >> 5;                       // 8 row-groups
  f32x4_t a0 = {0.f, 0.f, 0.f, 0.f};
  f32x4_t a1 = a0;
  int k = g;
  for (; k + 8 < n; k += 16) {
    float p0 = plist[k], p1 = plist[k + 8];
    f32x4_t r0 = *(const f32x4_t*)(ctx + (off + slist[k])     * DD + c4);
    f32x4_t r1 = *(const f32x4_t*)(ctx + (off + slist[k + 8]) * DD + c4);
    a0[0] += p0 * r0[0]; a0[1] += p0 * r0[1]; a0[2] += p0 * r0[2]; a0[3] += p0 * r0[3];
    a1[0] += p1 * r1[0]; a1[1] += p1 * r1[1]; a1[2] += p1 * r1[2]; a1[3] += p1 * r1[3];
  }
  for (; k < n; k += 8) {
    float p0 = plist[k];
    f32x4_t r0 = *(const f32x4_t*)(ctx + (off + slist[k]) * DD + c4);
    a0[0] += p0 * r0[0]; a0[1] += p0 * r0[1]; a0[2] += p0 * r0[2]; a0[3] += p0 * r0[3];
  }
  a0[0] += a1[0]; a0[1] += a1[1]; a0[2] += a1[2]; a0[3] += a1[3];
  part[tid] = a0;
  __syncthreads();
  if (tid < 32) {
    f32x4_t s = part[tid];
#pragma unroll
    for (int gg = 1; gg < 8; ++gg) {
      f32x4_t t = part[gg * 32 + tid];
      s[0] += t[0]; s[1] += t[1]; s[2] += t[2]; s[3] += t[3];
    }
    *(f32x4_t*)(&wpart[((long)b * WCH + c) * DD + tid * 4]) = s;
  }
}

// ---- K5: reduce partials, h = tanh([weighted,x]@Wout^T) ----
__global__ void k_out(const float* __restrict__ wpart, const float* __restrict__ inp,
                      const float* __restrict__ Wout, float* __restrict__ hout) {
  const int b = blockIdx.x;
  const int tid = threadIdx.x;                  // 128
  __shared__ float wsh[DD], xin[DD];
  float acc = 0.f;
#pragma unroll
  for (int cc = 0; cc < WCH; ++cc)
    acc += wpart[((long)b * WCH + cc) * DD + tid];
  wsh[tid] = acc;
  xin[tid] = inp[b * DD + tid];
  __syncthreads();
  const float* wr = Wout + tid * (2 * DD);
  float s = 0.f;
#pragma unroll 8
  for (int f = 0; f < DD; ++f) s += wsh[f] * wr[f];
#pragma unroll 8
  for (int f = 0; f < DD; ++f) s += xin[f] * wr[DD + f];
  hout[b * DD + tid] = tanhf(s);
}

extern "C" void kernel_launch(void* const* d_in, const int* in_sizes, int n_in,
                              void* d_out, int out_size, void* d_ws, size_t ws_size,
                              hipStream_t stream) {
  const float* inp  = (const float*)d_in[0];
  const float* ctx  = (const float*)d_in[1];
  const void*  mask = d_in[2];
  const float* Wg   = (const float*)d_in[3];
  const float* Vg   = (const float*)d_in[4];
  const float* Wout = (const float*)d_in[5];

  float* out = (float*)d_out;
  float* h_out = out;                 // [B, D]
  float* attn_out = out + BB * DD;    // [B, S]  (K2 writes raw logits here, K3 normalizes in place)

  char* ws = (char*)d_ws;
  unsigned int*   flag  = (unsigned int*)ws;
  unsigned short* Whi   = (unsigned short*)(ws + 1024);
  unsigned short* Wlo   = (unsigned short*)(ws + 1024 + 32768);
  float*          wv    = (float*)(ws + 1024 + 65536);
  float*          wpart = (float*)(ws + 1024 + 65536 + 65536);   // [B][WCH][DD] = 1 MB

  (void)hipMemsetAsync(flag, 0, 4, stream);
  k_detect  <<<dim3(256),     dim3(256), 0, stream>>>((const unsigned int*)mask, flag);
  k_prep    <<<dim3(BB),      dim3(DD),  0, stream>>>(inp, Wg, Vg, Whi, Wlo, wv);
  k_logits  <<<dim3(2, BB),   dim3(512), 0, stream>>>(ctx, Whi, Wlo, wv, attn_out);
  k_softmax <<<dim3(BB),      dim3(256), 0, stream>>>(attn_out, mask, flag, attn_out);
  k_wpartial<<<dim3(BB, WCH), dim3(256), 0, stream>>>(attn_out, ctx, wpart);
  k_out     <<<dim3(BB),      dim3(128), 0, stream>>>(wpart, inp, Wout, h_out);
}

// Round 8
// 244.495 us; speedup vs baseline: 1.0383x; 1.0383x over previous
//
#include <hip/hip_runtime.h>

// DeepAttention: h = tanh([attn@ctx, x] @ Wout^T-ish), attn = softmax(mask(w . relu(ctx@W^T)))
// R8: k_logits v5 — R6 structure (direct HBM A-frags, grid (4,B), no reg-dbuf) with
// chained hi/lo MFMA accumulator (-64 VALU/group) and launch_bounds(512,3).
// k_softmax 512 thr; k_wpartial 4-deep unroll.

#define BB 128
#define SS 8192
#define DD 128
#define WCH 16             // S-chunks for the weighted gather
#define WLEN (SS / WCH)    // 512 positions per gather block

typedef float f32x4_t __attribute__((ext_vector_type(4)));
typedef short bf16x8_t __attribute__((ext_vector_type(8)));
typedef unsigned short u16x8_t __attribute__((ext_vector_type(8)));
typedef unsigned int u32x4_t __attribute__((ext_vector_type(4)));

__device__ __forceinline__ unsigned short f2bf(float x) {
  unsigned u = __builtin_bit_cast(unsigned, x);
  unsigned r = (u + 0x7FFFu + ((u >> 16) & 1u)) >> 16;
  return (unsigned short)r;
}
__device__ __forceinline__ float bf2f(unsigned short h) {
  unsigned u = ((unsigned)h) << 16;
  return __builtin_bit_cast(float, u);
}
// hw pack: low16 = bf16(a), high16 = bf16(b)  (RNE)
__device__ __forceinline__ unsigned cvtpk(float a, float b) {
  unsigned r;
  asm("v_cvt_pk_bf16_f32 %0, %1, %2" : "=v"(r) : "v"(a), "v"(b));
  return r;
}

// ---- K0: detect mask storage format (0 = int32, 1 = uint8, 2 = float32) ----
__global__ void k_detect(const unsigned int* __restrict__ mw, unsigned int* __restrict__ flag) {
  int i = blockIdx.x * 256 + threadIdx.x;   // 256 blocks -> 65536 words = 256 KB
  unsigned v = mw[i];
  unsigned f = 0;
  if (v == 0x3F800000u) f = 2u;             // f32 1.0 pattern
  else if (v > 1u) f = 1u;                  // packed uint8 bools
  if (f) atomicOr(flag, f);
}

// ---- K1: merged prep. grid(128) x 128 thr.
// (a) W bf16 hi/lo split; (b) w[b,e] = relu(x@W^T)[b,e] * V[e], fp32 exact
__global__ void k_prep(const float* __restrict__ inp, const float* __restrict__ Wg,
                       const float* __restrict__ Vg, unsigned short* __restrict__ Whi,
                       unsigned short* __restrict__ Wlo, float* __restrict__ wv) {
  const int b = blockIdx.x, tid = threadIdx.x;
  {
    int i = b * DD + tid;
    float x = Wg[i];
    unsigned short h = f2bf(x);
    Whi[i] = h;
    Wlo[i] = f2bf(x - bf2f(h));
  }
  __shared__ float xin[DD];
  xin[tid] = inp[b * DD + tid];
  __syncthreads();
  const float* wr = Wg + tid * DD;
  float s = 0.f;
#pragma unroll 8
  for (int d = 0; d < DD; ++d) s += xin[d] * wr[d];
  wv[b * DD + tid] = fmaxf(s, 0.f) * Vg[tid];
}

// ---- K2 v5: logits[b,s] = sum_e w[b,e]*relu(sum_d ctx[b,s,d]*W[e,d]) ----
// A-fragments loaded straight from HBM (lane-exact), W hi/lo fragment-packed in LDS.
// Chained hi/lo MFMA accumulator. No barriers in the main loop. grid (4, BB), 512 thr.
__launch_bounds__(512, 3)
__global__ void k_logits(const float* __restrict__ ctx, const unsigned short* __restrict__ Whi,
                         const unsigned short* __restrict__ Wlo, const float* __restrict__ wv,
                         float* __restrict__ logits) {
  __shared__ unsigned short WPKH[16384];     // 32 KB: W-hi, fragment-packed
  __shared__ unsigned short WPKL[16384];     // 32 KB: W-lo
  __shared__ float wl[DD];

  const int tid = threadIdx.x;
  const int b = blockIdx.y;
  const int slice = blockIdx.x;              // 0..3, 2048 rows each

  // Stage W hi/lo into packed-fragment layout. Packed unit p (16B) = frag p>>6, lane p&63.
#pragma unroll
  for (int jj = 0; jj < 4; ++jj) {
    int p = tid + jj * 512;                  // 2048 units per array
    int frag = p >> 6;                       // et*4 + ks
    int li = p & 63;
    int et = frag >> 2, ks = frag & 3;
    int lg2 = li >> 4, lr2 = li & 15;
    int src = (et * 16 + lr2) * DD + ks * 32 + lg2 * 8;
    *(u16x8_t*)(&WPKH[p * 8]) = *(const u16x8_t*)(&Whi[src]);
    *(u16x8_t*)(&WPKL[p * 8]) = *(const u16x8_t*)(&Wlo[src]);
  }
  if (tid < DD) wl[tid] = wv[b * DD + tid];
  __syncthreads();

  const int wave = tid >> 6;
  const int lane = tid & 63;
  const int lr = lane & 15;
  const int lg = lane >> 4;

  float wfreg[8];
#pragma unroll
  for (int et = 0; et < 8; ++et) wfreg[et] = wl[et * 16 + lr];

  // wave owns 256 contiguous rows; 8 groups of 32 rows (2 row-tiles of 16)
  const long rowb0 = (long)b * SS + (long)slice * 2048 + (long)wave * 256;

#pragma unroll 1
  for (int g = 0; g < 8; ++g) {
    const long grow = rowb0 + g * 32;
    // ---- load A-fragments straight from HBM, convert f32 -> bf16 in-register ----
    bf16x8_t a[2][4];
#pragma unroll
    for (int rt = 0; rt < 2; ++rt) {
      const float* rp = ctx + (grow + rt * 16 + lr) * (long)DD + lg * 8;
#pragma unroll
      for (int ks = 0; ks < 4; ++ks) {
        f32x4_t x0 = *(const f32x4_t*)(rp + ks * 32);
        f32x4_t x1 = *(const f32x4_t*)(rp + ks * 32 + 4);
        u32x4_t hh;
        hh[0] = cvtpk(x0[0], x0[1]);
        hh[1] = cvtpk(x0[2], x0[3]);
        hh[2] = cvtpk(x1[0], x1[1]);
        hh[3] = cvtpk(x1[2], x1[3]);
        a[rt][ks] = __builtin_bit_cast(bf16x8_t, hh);
      }
    }
    // ---- compute: 8 et-tiles of W, 2 row-tiles, chained hi+lo accumulator ----
    float part[2][4] = {{0.f, 0.f, 0.f, 0.f}, {0.f, 0.f, 0.f, 0.f}};
#pragma unroll
    for (int et = 0; et < 8; ++et) {
      bf16x8_t bh[4], bl[4];
#pragma unroll
      for (int ks = 0; ks < 4; ++ks) {
        const int pidx = ((((et << 2) | ks) << 6) | lane) << 3;
        bh[ks] = *(const bf16x8_t*)(&WPKH[pidx]);
        bl[ks] = *(const bf16x8_t*)(&WPKL[pidx]);
      }
      const float wf = wfreg[et];
#pragma unroll
      for (int rt = 0; rt < 2; ++rt) {
        f32x4_t v = {0.f, 0.f, 0.f, 0.f};
#pragma unroll
        for (int ks = 0; ks < 4; ++ks) {
          v = __builtin_amdgcn_mfma_f32_16x16x32_bf16(a[rt][ks], bh[ks], v, 0, 0, 0);
          v = __builtin_amdgcn_mfma_f32_16x16x32_bf16(a[rt][ks], bl[ks], v, 0, 0, 0);
        }
#pragma unroll
        for (int i = 0; i < 4; ++i)
          part[rt][i] += wf * fmaxf(v[i], 0.f);
      }
    }
    // ---- reduce over e (16 lanes share a row), store ----
#pragma unroll
    for (int rt = 0; rt < 2; ++rt) {
#pragma unroll
      for (int m = 1; m < 16; m <<= 1) {
        part[rt][0] += __shfl_xor(part[rt][0], m, 64);
        part[rt][1] += __shfl_xor(part[rt][1], m, 64);
        part[rt][2] += __shfl_xor(part[rt][2], m, 64);
        part[rt][3] += __shfl_xor(part[rt][3], m, 64);
      }
    }
    if (lr == 0) {                            // C row = 4*lg + i
      long so = grow + lg * 4;
      logits[so + 0]  = part[0][0];
      logits[so + 1]  = part[0][1];
      logits[so + 2]  = part[0][2];
      logits[so + 3]  = part[0][3];
      logits[so + 16] = part[1][0];
      logits[so + 17] = part[1][1];
      logits[so + 18] = part[1][2];
      logits[so + 19] = part[1][3];
    }
  }
}

// ---- K3: masked softmax over S per batch, in place over logits. 512 thr ----
__global__ void k_softmax(const float* __restrict__ logits, const void* __restrict__ mask,
                          const unsigned int* __restrict__ flag, float* __restrict__ attn) {
  const int b = blockIdx.x;
  const int tid = threadIdx.x;                  // 512
  __shared__ float buf[SS];                     // 32 KiB
  __shared__ float red[8];
  const unsigned mode = *flag;
  const long off = (long)b * SS;
  float mx = -3.4e38f;
  for (int i = tid; i < SS; i += 512) {
    float v = logits[off + i];
    bool m;
    if (mode == 0)      m = ((const int*)mask)[off + i] != 0;
    else if (mode == 1) m = ((const unsigned char*)mask)[off + i] != 0;
    else                m = ((const float*)mask)[off + i] != 0.f;
    if (m) v = -1e12f;
    buf[i] = v;
    mx = fmaxf(mx, v);
  }
#pragma unroll
  for (int m2 = 32; m2; m2 >>= 1) mx = fmaxf(mx, __shfl_xor(mx, m2, 64));
  if ((tid & 63) == 0) red[tid >> 6] = mx;
  __syncthreads();
  mx = red[0];
#pragma unroll
  for (int i = 1; i < 8; ++i) mx = fmaxf(mx, red[i]);
  float sum = 0.f;
  for (int i = tid; i < SS; i += 512) {
    float e = expf(buf[i] - mx);
    buf[i] = e;
    sum += e;
  }
#pragma unroll
  for (int m2 = 32; m2; m2 >>= 1) sum += __shfl_xor(sum, m2, 64);
  __syncthreads();
  if ((tid & 63) == 0) red[tid >> 6] = sum;
  __syncthreads();
  float tot = 0.f;
#pragma unroll
  for (int i = 0; i < 8; ++i) tot += red[i];
  float inv = 1.f / tot;
  for (int i = tid; i < SS; i += 512) attn[off + i] = buf[i] * inv;
}

// ---- K4: partial weighted sums. grid (B, WCH), 256 thr. wpart[b][c][d] ----
// f32x4 per lane: 32 lanes cover a row; 8 groups x 4-deep unroll = 32 rows in flight.
__global__ void k_wpartial(const float* __restrict__ attn, const float* __restrict__ ctx,
                           float* __restrict__ wpart) {
  const int b = blockIdx.x, c = blockIdx.y;
  const int tid = threadIdx.x;                  // 256
  __shared__ unsigned short slist[WLEN];
  __shared__ float plist[WLEN];
  __shared__ f32x4_t part[256];                 // 4 KB
  __shared__ unsigned cnt;
  if (tid == 0) cnt = 0;
  __syncthreads();
  const long off = (long)b * SS + (long)c * WLEN;
  for (int i = tid; i < WLEN; i += 256) {
    float p = attn[off + i];
    if (p > 1e-8f) {                            // skipped mass <= 8192*1e-8*|ctx| ~ 5e-4
      unsigned k = atomicAdd(&cnt, 1u);
      slist[k] = (unsigned short)i;
      plist[k] = p;
    }
  }
  __syncthreads();
  const int n = (int)cnt;
  const int c4 = (tid & 31) * 4;
  const int g = tid >> 5;                       // 8 row-groups
  f32x4_t a0 = {0.f, 0.f, 0.f, 0.f};
  f32x4_t a1 = a0, a2 = a0, a3 = a0;
  int k = g;
  for (; k + 24 < n; k += 32) {
    float p0 = plist[k], p1 = plist[k + 8], p2 = plist[k + 16], p3 = plist[k + 24];
    f32x4_t r0 = *(const f32x4_t*)(ctx + (off + slist[k])      * DD + c4);
    f32x4_t r1 = *(const f32x4_t*)(ctx + (off + slist[k + 8])  * DD + c4);
    f32x4_t r2 = *(const f32x4_t*)(ctx + (off + slist[k + 16]) * DD + c4);
    f32x4_t r3 = *(const f32x4_t*)(ctx + (off + slist[k + 24]) * DD + c4);
    a0[0] += p0 * r0[0]; a0[1] += p0 * r0[1]; a0[2] += p0 * r0[2]; a0[3] += p0 * r0[3];
    a1[0] += p1 * r1[0]; a1[1] += p1 * r1[1]; a1[2] += p1 * r1[2]; a1[3] += p1 * r1[3];
    a2[0] += p2 * r2[0]; a2[1] += p2 * r2[1]; a2[2] += p2 * r2[2]; a2[3] += p2 * r2[3];
    a3[0] += p3 * r3[0]; a3[1] += p3 * r3[1]; a3[2] += p3 * r3[2]; a3[3] += p3 * r3[3];
  }
  for (; k < n; k += 8) {
    float p0 = plist[k];
    f32x4_t r0 = *(const f32x4_t*)(ctx + (off + slist[k]) * DD + c4);
    a0[0] += p0 * r0[0]; a0[1] += p0 * r0[1]; a0[2] += p0 * r0[2]; a0[3] += p0 * r0[3];
  }
  a0[0] += a1[0] + a2[0] + a3[0];
  a0[1] += a1[1] + a2[1] + a3[1];
  a0[2] += a1[2] + a2[2] + a3[2];
  a0[3] += a1[3] + a2[3] + a3[3];
  part[tid] = a0;
  __syncthreads();
  if (tid < 32) {
    f32x4_t s = part[tid];
#pragma unroll
    for (int gg = 1; gg < 8; ++gg) {
      f32x4_t t = part[gg * 32 + tid];
      s[0] += t[0]; s[1] += t[1]; s[2] += t[2]; s[3] += t[3];
    }
    *(f32x4_t*)(&wpart[((long)b * WCH + c) * DD + tid * 4]) = s;
  }
}

// ---- K5: reduce partials, h = tanh([weighted,x]@Wout^T) ----
__global__ void k_out(const float* __restrict__ wpart, const float* __restrict__ inp,
                      const float* __restrict__ Wout, float* __restrict__ hout) {
  const int b = blockIdx.x;
  const int tid = threadIdx.x;                  // 128
  __shared__ float wsh[DD], xin[DD];
  float acc = 0.f;
#pragma unroll
  for (int cc = 0; cc < WCH; ++cc)
    acc += wpart[((long)b * WCH + cc) * DD + tid];
  wsh[tid] = acc;
  xin[tid] = inp[b * DD + tid];
  __syncthreads();
  const float* wr = Wout + tid * (2 * DD);
  float s = 0.f;
#pragma unroll 8
  for (int f = 0; f < DD; ++f) s += wsh[f] * wr[f];
#pragma unroll 8
  for (int f = 0; f < DD; ++f) s += xin[f] * wr[DD + f];
  hout[b * DD + tid] = tanhf(s);
}

extern "C" void kernel_launch(void* const* d_in, const int* in_sizes, int n_in,
                              void* d_out, int out_size, void* d_ws, size_t ws_size,
                              hipStream_t stream) {
  const float* inp  = (const float*)d_in[0];
  const float* ctx  = (const float*)d_in[1];
  const void*  mask = d_in[2];
  const float* Wg   = (const float*)d_in[3];
  const float* Vg   = (const float*)d_in[4];
  const float* Wout = (const float*)d_in[5];

  float* out = (float*)d_out;
  float* h_out = out;                 // [B, D]
  float* attn_out = out + BB * DD;    // [B, S]  (K2 writes raw logits here, K3 normalizes in place)

  char* ws = (char*)d_ws;
  unsigned int*   flag  = (unsigned int*)ws;
  unsigned short* Whi   = (unsigned short*)(ws + 1024);
  unsigned short* Wlo   = (unsigned short*)(ws + 1024 + 32768);
  float*          wv    = (float*)(ws + 1024 + 65536);
  float*          wpart = (float*)(ws + 1024 + 65536 + 65536);   // [B][WCH][DD] = 1 MB

  (void)hipMemsetAsync(flag, 0, 4, stream);
  k_detect  <<<dim3(256),     dim3(256), 0, stream>>>((const unsigned int*)mask, flag);
  k_prep    <<<dim3(BB),      dim3(DD),  0, stream>>>(inp, Wg, Vg, Whi, Wlo, wv);
  k_logits  <<<dim3(4, BB),   dim3(512), 0, stream>>>(ctx, Whi, Wlo, wv, attn_out);
  k_softmax <<<dim3(BB),      dim3(512), 0, stream>>>(attn_out, mask, flag, attn_out);
  k_wpartial<<<dim3(BB, WCH), dim3(256), 0, stream>>>(attn_out, ctx, wpart);
  k_out     <<<dim3(BB),      dim3(128), 0, stream>>>(wpart, inp, Wout, h_out);
}

// Round 9
// 220.671 us; speedup vs baseline: 1.1504x; 1.1080x over previous
//
#include <hip/hip_runtime.h>

// DeepAttention: h = tanh([attn@ctx, x] @ Wout^T-ish), attn = softmax(mask(w . relu(ctx@W^T)))
// R9: k_logits = R6-exact v3b (best known: 231.9us). NEW: k_softmax deleted — k_stats
// (mask + per-half max/sumexp) + softmax applied on-the-fly inside k_wpartial.

#define BB 128
#define SS 8192
#define DD 128
#define WCH 16             // S-chunks for the weighted gather
#define WLEN (SS / WCH)    // 512 positions per gather block

typedef float f32x4_t __attribute__((ext_vector_type(4)));
typedef short bf16x8_t __attribute__((ext_vector_type(8)));
typedef unsigned short u16x8_t __attribute__((ext_vector_type(8)));
typedef unsigned int u32x4_t __attribute__((ext_vector_type(4)));

__device__ __forceinline__ unsigned short f2bf(float x) {
  unsigned u = __builtin_bit_cast(unsigned, x);
  unsigned r = (u + 0x7FFFu + ((u >> 16) & 1u)) >> 16;
  return (unsigned short)r;
}
__device__ __forceinline__ float bf2f(unsigned short h) {
  unsigned u = ((unsigned)h) << 16;
  return __builtin_bit_cast(float, u);
}
// hw pack: low16 = bf16(a), high16 = bf16(b)  (RNE)
__device__ __forceinline__ unsigned cvtpk(float a, float b) {
  unsigned r;
  asm("v_cvt_pk_bf16_f32 %0, %1, %2" : "=v"(r) : "v"(a), "v"(b));
  return r;
}

// ---- K0: detect mask storage format (0 = int32, 1 = uint8, 2 = float32) ----
__global__ void k_detect(const unsigned int* __restrict__ mw, unsigned int* __restrict__ flag) {
  int i = blockIdx.x * 256 + threadIdx.x;   // 256 blocks -> 65536 words = 256 KB
  unsigned v = mw[i];
  unsigned f = 0;
  if (v == 0x3F800000u) f = 2u;             // f32 1.0 pattern
  else if (v > 1u) f = 1u;                  // packed uint8 bools
  if (f) atomicOr(flag, f);
}

// ---- K1: merged prep. grid(128) x 128 thr.
// (a) W bf16 hi/lo split; (b) w[b,e] = relu(x@W^T)[b,e] * V[e], fp32 exact
__global__ void k_prep(const float* __restrict__ inp, const float* __restrict__ Wg,
                       const float* __restrict__ Vg, unsigned short* __restrict__ Whi,
                       unsigned short* __restrict__ Wlo, float* __restrict__ wv) {
  const int b = blockIdx.x, tid = threadIdx.x;
  {
    int i = b * DD + tid;
    float x = Wg[i];
    unsigned short h = f2bf(x);
    Whi[i] = h;
    Wlo[i] = f2bf(x - bf2f(h));
  }
  __shared__ float xin[DD];
  xin[tid] = inp[b * DD + tid];
  __syncthreads();
  const float* wr = Wg + tid * DD;
  float s = 0.f;
#pragma unroll 8
  for (int d = 0; d < DD; ++d) s += xin[d] * wr[d];
  wv[b * DD + tid] = fmaxf(s, 0.f) * Vg[tid];
}

// ---- K2: R6-exact v3b. logits[b,s] = sum_e w[b,e]*relu(sum_d ctx[b,s,d]*W[e,d]) ----
__launch_bounds__(512, 2)
__global__ void k_logits(const float* __restrict__ ctx, const unsigned short* __restrict__ Whi,
                         const unsigned short* __restrict__ Wlo, const float* __restrict__ wv,
                         float* __restrict__ logits) {
  __shared__ unsigned short WPKH[16384];     // 32 KB: W-hi, fragment-packed
  __shared__ unsigned short WPKL[16384];     // 32 KB: W-lo
  __shared__ float wl[DD];

  const int tid = threadIdx.x;
  const int b = blockIdx.y;
  const int slice = blockIdx.x;              // 0..3, 2048 rows each

  // Stage W hi/lo into packed-fragment layout. Packed unit p (16B) = frag p>>6, lane p&63.
#pragma unroll
  for (int jj = 0; jj < 4; ++jj) {
    int p = tid + jj * 512;                  // 2048 units per array
    int frag = p >> 6;                       // et*4 + ks
    int li = p & 63;
    int et = frag >> 2, ks = frag & 3;
    int lg2 = li >> 4, lr2 = li & 15;
    int src = (et * 16 + lr2) * DD + ks * 32 + lg2 * 8;
    *(u16x8_t*)(&WPKH[p * 8]) = *(const u16x8_t*)(&Whi[src]);
    *(u16x8_t*)(&WPKL[p * 8]) = *(const u16x8_t*)(&Wlo[src]);
  }
  if (tid < DD) wl[tid] = wv[b * DD + tid];
  __syncthreads();

  const int wave = tid >> 6;
  const int lane = tid & 63;
  const int lr = lane & 15;
  const int lg = lane >> 4;

  float wfreg[8];
#pragma unroll
  for (int et = 0; et < 8; ++et) wfreg[et] = wl[et * 16 + lr];

  // wave owns 256 contiguous rows; 8 groups of 32 rows (2 row-tiles of 16)
  const long rowb0 = (long)b * SS + (long)slice * 2048 + (long)wave * 256;

#pragma unroll 1
  for (int g = 0; g < 8; ++g) {
    const long grow = rowb0 + g * 32;
    // ---- load A-fragments straight from HBM, convert f32 -> bf16 in-register ----
    bf16x8_t a[2][4];
#pragma unroll
    for (int rt = 0; rt < 2; ++rt) {
      const float* rp = ctx + (grow + rt * 16 + lr) * (long)DD + lg * 8;
#pragma unroll
      for (int ks = 0; ks < 4; ++ks) {
        f32x4_t x0 = *(const f32x4_t*)(rp + ks * 32);
        f32x4_t x1 = *(const f32x4_t*)(rp + ks * 32 + 4);
        u32x4_t hh;
        hh[0] = cvtpk(x0[0], x0[1]);
        hh[1] = cvtpk(x0[2], x0[3]);
        hh[2] = cvtpk(x1[0], x1[1]);
        hh[3] = cvtpk(x1[2], x1[3]);
        a[rt][ks] = __builtin_bit_cast(bf16x8_t, hh);
      }
    }
    // ---- compute: 8 et-tiles of W, 2 row-tiles, hi+lo splits ----
    float part[2][4] = {{0.f, 0.f, 0.f, 0.f}, {0.f, 0.f, 0.f, 0.f}};
#pragma unroll
    for (int et = 0; et < 8; ++et) {
      bf16x8_t bh[4], bl[4];
#pragma unroll
      for (int ks = 0; ks < 4; ++ks) {
        const int pidx = ((((et << 2) | ks) << 6) | lane) << 3;
        bh[ks] = *(const bf16x8_t*)(&WPKH[pidx]);
        bl[ks] = *(const bf16x8_t*)(&WPKL[pidx]);
      }
      const float wf = wfreg[et];
#pragma unroll
      for (int rt = 0; rt < 2; ++rt) {
        f32x4_t v1 = {0.f, 0.f, 0.f, 0.f};
        f32x4_t v2 = v1;
#pragma unroll
        for (int ks = 0; ks < 4; ++ks) {
          v1 = __builtin_amdgcn_mfma_f32_16x16x32_bf16(a[rt][ks], bh[ks], v1, 0, 0, 0);
          v2 = __builtin_amdgcn_mfma_f32_16x16x32_bf16(a[rt][ks], bl[ks], v2, 0, 0, 0);
        }
#pragma unroll
        for (int i = 0; i < 4; ++i)
          part[rt][i] += wf * fmaxf(v1[i] + v2[i], 0.f);
      }
    }
    // ---- reduce over e (16 lanes share a row), store ----
#pragma unroll
    for (int rt = 0; rt < 2; ++rt) {
#pragma unroll
      for (int m = 1; m < 16; m <<= 1) {
        part[rt][0] += __shfl_xor(part[rt][0], m, 64);
        part[rt][1] += __shfl_xor(part[rt][1], m, 64);
        part[rt][2] += __shfl_xor(part[rt][2], m, 64);
        part[rt][3] += __shfl_xor(part[rt][3], m, 64);
      }
    }
    if (lr == 0) {                            // C row = 4*lg + i
      long so = grow + lg * 4;
      logits[so + 0]  = part[0][0];
      logits[so + 1]  = part[0][1];
      logits[so + 2]  = part[0][2];
      logits[so + 3]  = part[0][3];
      logits[so + 16] = part[1][0];
      logits[so + 17] = part[1][1];
      logits[so + 18] = part[1][2];
      logits[so + 19] = part[1][3];
    }
  }
}

// ---- K3: stats. grid (B, 2), 256 thr. Applies mask in place; writes per-half (max, sumexp).
__global__ void k_stats(float* logits, const void* __restrict__ mask,
                        const unsigned int* __restrict__ flag, float* __restrict__ stats) {
  const int b = blockIdx.x, h = blockIdx.y;
  const int tid = threadIdx.x;                  // 256; half = 4096 elems -> 16/thread
  const unsigned mode = *flag;
  const long off = (long)b * SS + (long)h * 4096;
  __shared__ float red[4];
  float vals[16];
  float mx = -3.4e38f;
#pragma unroll
  for (int j = 0; j < 16; ++j) {
    long i = off + tid + j * 256;
    float v = logits[i];
    bool m;
    if (mode == 0)      m = ((const int*)mask)[i] != 0;
    else if (mode == 1) m = ((const unsigned char*)mask)[i] != 0;
    else                m = ((const float*)mask)[i] != 0.f;
    if (m) v = -1e12f;
    vals[j] = v;
    logits[i] = v;                              // masked logits persisted for k_wpartial
    mx = fmaxf(mx, v);
  }
#pragma unroll
  for (int m2 = 32; m2; m2 >>= 1) mx = fmaxf(mx, __shfl_xor(mx, m2, 64));
  if ((tid & 63) == 0) red[tid >> 6] = mx;
  __syncthreads();
  mx = fmaxf(fmaxf(red[0], red[1]), fmaxf(red[2], red[3]));
  float s = 0.f;
#pragma unroll
  for (int j = 0; j < 16; ++j) s += expf(vals[j] - mx);
#pragma unroll
  for (int m2 = 32; m2; m2 >>= 1) s += __shfl_xor(s, m2, 64);
  __syncthreads();
  if ((tid & 63) == 0) red[tid >> 6] = s;
  __syncthreads();
  if (tid == 0) {
    stats[(b * 2 + h) * 2 + 0] = mx;
    stats[(b * 2 + h) * 2 + 1] = red[0] + red[1] + red[2] + red[3];
  }
}

// ---- K4: softmax-on-the-fly + partial weighted sums. grid (B, WCH), 256 thr ----
// attnbuf aliases the masked-logits buffer: read l, write p in place.
__global__ void k_wpartial(float* attnbuf, const float* __restrict__ stats,
                           const float* __restrict__ ctx, float* __restrict__ wpart) {
  const int b = blockIdx.x, c = blockIdx.y;
  const int tid = threadIdx.x;                  // 256
  __shared__ unsigned short slist[WLEN];
  __shared__ float plist[WLEN];
  __shared__ f32x4_t part[256];                 // 4 KB
  __shared__ unsigned cnt;
  if (tid == 0) cnt = 0;
  __syncthreads();
  const float m0 = stats[b * 4 + 0], s0 = stats[b * 4 + 1];
  const float m1 = stats[b * 4 + 2], s1 = stats[b * 4 + 3];
  const float M = fmaxf(m0, m1);
  const float inv = 1.f / (s0 * expf(m0 - M) + s1 * expf(m1 - M));
  const long off = (long)b * SS + (long)c * WLEN;
  for (int i = tid; i < WLEN; i += 256) {
    float p = expf(attnbuf[off + i] - M) * inv;
    attnbuf[off + i] = p;                       // final attn output
    if (p > 1e-8f) {                            // skipped mass <= 8192*1e-8*|ctx| ~ 5e-4
      unsigned k = atomicAdd(&cnt, 1u);
      slist[k] = (unsigned short)i;
      plist[k] = p;
    }
  }
  __syncthreads();
  const int n = (int)cnt;
  const int c4 = (tid & 31) * 4;
  const int g = tid >> 5;                       // 8 row-groups
  f32x4_t a0 = {0.f, 0.f, 0.f, 0.f};
  f32x4_t a1 = a0;
  int k = g;
  for (; k + 8 < n; k += 16) {
    float p0 = plist[k], p1 = plist[k + 8];
    f32x4_t r0 = *(const f32x4_t*)(ctx + (off + slist[k])     * DD + c4);
    f32x4_t r1 = *(const f32x4_t*)(ctx + (off + slist[k + 8]) * DD + c4);
    a0[0] += p0 * r0[0]; a0[1] += p0 * r0[1]; a0[2] += p0 * r0[2]; a0[3] += p0 * r0[3];
    a1[0] += p1 * r1[0]; a1[1] += p1 * r1[1]; a1[2] += p1 * r1[2]; a1[3] += p1 * r1[3];
  }
  for (; k < n; k += 8) {
    float p0 = plist[k];
    f32x4_t r0 = *(const f32x4_t*)(ctx + (off + slist[k]) * DD + c4);
    a0[0] += p0 * r0[0]; a0[1] += p0 * r0[1]; a0[2] += p0 * r0[2]; a0[3] += p0 * r0[3];
  }
  a0[0] += a1[0]; a0[1] += a1[1]; a0[2] += a1[2]; a0[3] += a1[3];
  part[tid] = a0;
  __syncthreads();
  if (tid < 32) {
    f32x4_t s = part[tid];
#pragma unroll
    for (int gg = 1; gg < 8; ++gg) {
      f32x4_t t = part[gg * 32 + tid];
      s[0] += t[0]; s[1] += t[1]; s[2] += t[2]; s[3] += t[3];
    }
    *(f32x4_t*)(&wpart[((long)b * WCH + c) * DD + tid * 4]) = s;
  }
}

// ---- K5: reduce partials, h = tanh([weighted,x]@Wout^T) ----
__global__ void k_out(const float* __restrict__ wpart, const float* __restrict__ inp,
                      const float* __restrict__ Wout, float* __restrict__ hout) {
  const int b = blockIdx.x;
  const int tid = threadIdx.x;                  // 128
  __shared__ float wsh[DD], xin[DD];
  float acc = 0.f;
#pragma unroll
  for (int cc = 0; cc < WCH; ++cc)
    acc += wpart[((long)b * WCH + cc) * DD + tid];
  wsh[tid] = acc;
  xin[tid] = inp[b * DD + tid];
  __syncthreads();
  const float* wr = Wout + tid * (2 * DD);
  float s = 0.f;
#pragma unroll 8
  for (int f = 0; f < DD; ++f) s += wsh[f] * wr[f];
#pragma unroll 8
  for (int f = 0; f < DD; ++f) s += xin[f] * wr[DD + f];
  hout[b * DD + tid] = tanhf(s);
}

extern "C" void kernel_launch(void* const* d_in, const int* in_sizes, int n_in,
                              void* d_out, int out_size, void* d_ws, size_t ws_size,
                              hipStream_t stream) {
  const float* inp  = (const float*)d_in[0];
  const float* ctx  = (const float*)d_in[1];
  const void*  mask = d_in[2];
  const float* Wg   = (const float*)d_in[3];
  const float* Vg   = (const float*)d_in[4];
  const float* Wout = (const float*)d_in[5];

  float* out = (float*)d_out;
  float* h_out = out;                 // [B, D]
  float* attn_out = out + BB * DD;    // [B, S]  (logits -> masked logits -> attn, in place)

  char* ws = (char*)d_ws;
  unsigned int*   flag  = (unsigned int*)ws;
  unsigned short* Whi   = (unsigned short*)(ws + 1024);
  unsigned short* Wlo   = (unsigned short*)(ws + 1024 + 32768);
  float*          wv    = (float*)(ws + 1024 + 65536);
  float*          wpart = (float*)(ws + 1024 + 65536 + 65536);             // [B][WCH][DD] = 1 MB
  float*          stats = (float*)(ws + 1024 + 65536 + 65536 + 1048576);   // [B][2][2] = 2 KB

  (void)hipMemsetAsync(flag, 0, 4, stream);
  k_detect  <<<dim3(256),     dim3(256), 0, stream>>>((const unsigned int*)mask, flag);
  k_prep    <<<dim3(BB),      dim3(DD),  0, stream>>>(inp, Wg, Vg, Whi, Wlo, wv);
  k_logits  <<<dim3(4, BB),   dim3(512), 0, stream>>>(ctx, Whi, Wlo, wv, attn_out);
  k_stats   <<<dim3(BB, 2),   dim3(256), 0, stream>>>(attn_out, mask, flag, stats);
  k_wpartial<<<dim3(BB, WCH), dim3(256), 0, stream>>>(attn_out, stats, ctx, wpart);
  k_out     <<<dim3(BB),      dim3(128), 0, stream>>>(wpart, inp, Wout, h_out);
}

// Round 10
// 167.159 us; speedup vs baseline: 1.5187x; 1.3201x over previous
//
#include <hip/hip_runtime.h>

// DeepAttention: h = tanh([attn@ctx, x] @ Wout^T-ish), attn = softmax(mask(w . relu(ctx@W^T)))
// R10: flash-style full fusion — k_logits computes logits AND the online-softmax weighted
// sum (ctx read exactly once). Per-wave (m,s,W[32regs]) with rescale; per-block slice
// combine; k_attn normalizes attn; k_final combines slices + tanh GEMM.

#define BB 128
#define SS 8192
#define DD 128

typedef float f32x4_t __attribute__((ext_vector_type(4)));
typedef short bf16x8_t __attribute__((ext_vector_type(8)));
typedef unsigned short u16x8_t __attribute__((ext_vector_type(8)));
typedef unsigned int u32x4_t __attribute__((ext_vector_type(4)));
typedef int i32x4_t __attribute__((ext_vector_type(4)));

__device__ __forceinline__ unsigned short f2bf(float x) {
  unsigned u = __builtin_bit_cast(unsigned, x);
  unsigned r = (u + 0x7FFFu + ((u >> 16) & 1u)) >> 16;
  return (unsigned short)r;
}
__device__ __forceinline__ float bf2f(unsigned short h) {
  unsigned u = ((unsigned)h) << 16;
  return __builtin_bit_cast(float, u);
}
// hw pack: low16 = bf16(a), high16 = bf16(b)  (RNE)
__device__ __forceinline__ unsigned cvtpk(float a, float b) {
  unsigned r;
  asm("v_cvt_pk_bf16_f32 %0, %1, %2" : "=v"(r) : "v"(a), "v"(b));
  return r;
}

// ---- K0: detect mask storage format (0 = int32, 1 = uint8, 2 = float32) ----
__global__ void k_detect(const unsigned int* __restrict__ mw, unsigned int* __restrict__ flag) {
  int i = blockIdx.x * 256 + threadIdx.x;   // 256 blocks -> 65536 words = 256 KB
  unsigned v = mw[i];
  unsigned f = 0;
  if (v == 0x3F800000u) f = 2u;             // f32 1.0 pattern
  else if (v > 1u) f = 1u;                  // packed uint8 bools
  if (f) atomicOr(flag, f);
}

// ---- K1: merged prep. grid(128) x 128 thr.
// (a) W bf16 hi/lo split; (b) w[b,e] = relu(x@W^T)[b,e] * V[e], fp32 exact
__global__ void k_prep(const float* __restrict__ inp, const float* __restrict__ Wg,
                       const float* __restrict__ Vg, unsigned short* __restrict__ Whi,
                       unsigned short* __restrict__ Wlo, float* __restrict__ wv) {
  const int b = blockIdx.x, tid = threadIdx.x;
  {
    int i = b * DD + tid;
    float x = Wg[i];
    unsigned short h = f2bf(x);
    Whi[i] = h;
    Wlo[i] = f2bf(x - bf2f(h));
  }
  __shared__ float xin[DD];
  xin[tid] = inp[b * DD + tid];
  __syncthreads();
  const float* wr = Wg + tid * DD;
  float s = 0.f;
#pragma unroll 8
  for (int d = 0; d < DD; ++d) s += xin[d] * wr[d];
  wv[b * DD + tid] = fmaxf(s, 0.f) * Vg[tid];
}

// ---- K2: fused logits + mask + online-softmax weighted accumulation ----
// grid (4, BB), 512 thr. Per wave: 256 rows in 16 tiles of 16 rows (rt in {0,1} per 32-row
// group). ctx rows live in regs: logit via MFMA, then p=exp(l-m) permuted to holder lanes
// and FMA'd into W_acc from the exact f32 ctx regs.
__launch_bounds__(512, 1)
__global__ void k_logits(const float* __restrict__ ctx, const unsigned short* __restrict__ Whi,
                         const unsigned short* __restrict__ Wlo, const float* __restrict__ wv,
                         const void* __restrict__ maskp, const unsigned int* __restrict__ flag,
                         float* __restrict__ logits, float* __restrict__ Wslice,
                         float* __restrict__ stats) {
  __shared__ unsigned short WPKH[16384];     // 32 KB: W-hi, fragment-packed
  __shared__ unsigned short WPKL[16384];     // 32 KB: W-lo
  __shared__ float wl[DD];
  __shared__ float WB[8][DD];                // 4 KB: per-wave weighted vectors
  __shared__ float MS[8][2];                 // per-wave (m, s)

  const int tid = threadIdx.x;
  const int b = blockIdx.y;
  const int slice = blockIdx.x;              // 0..3, 2048 rows each
  const int wave = tid >> 6;
  const int lane = tid & 63;
  const int lr = lane & 15;
  const int lg = lane >> 4;
  const unsigned mode = *flag;

  const long rowb0 = (long)b * SS + (long)slice * 2048 + (long)wave * 256;

  f32x4_t xA[8], xB[8];
  auto issue = [&](f32x4_t (&x)[8], long grow, int rt) {
    const float* rp = ctx + (grow + rt * 16 + lr) * (long)DD + lg * 8;
#pragma unroll
    for (int ks = 0; ks < 4; ++ks) {
      x[ks * 2]     = *(const f32x4_t*)(rp + ks * 32);
      x[ks * 2 + 1] = *(const f32x4_t*)(rp + ks * 32 + 4);
    }
  };

  issue(xA, rowb0, 0);                       // first tile's loads fly under W staging

  // Stage W hi/lo into packed-fragment layout. Packed unit p (16B) = frag p>>6, lane p&63.
#pragma unroll
  for (int jj = 0; jj < 4; ++jj) {
    int p = tid + jj * 512;                  // 2048 units per array
    int frag = p >> 6;                       // et*4 + ks
    int li = p & 63;
    int et = frag >> 2, ks = frag & 3;
    int lg2 = li >> 4, lr2 = li & 15;
    int src = (et * 16 + lr2) * DD + ks * 32 + lg2 * 8;
    *(u16x8_t*)(&WPKH[p * 8]) = *(const u16x8_t*)(&Whi[src]);
    *(u16x8_t*)(&WPKL[p * 8]) = *(const u16x8_t*)(&Wlo[src]);
  }
  if (tid < DD) wl[tid] = wv[b * DD + tid];
  __syncthreads();

  float wfreg[8];
#pragma unroll
  for (int et = 0; et < 8; ++et) wfreg[et] = wl[et * 16 + lr];

  float m_run = -3.4e38f, s_run = 0.f;
  f32x4_t wacc[8];
#pragma unroll
  for (int k = 0; k < 8; ++k) wacc[k] = f32x4_t{0.f, 0.f, 0.f, 0.f};

  auto process = [&](const f32x4_t (&x)[8], long grow, int rt) {
    // f32 -> bf16 A-fragments
    bf16x8_t a[4];
#pragma unroll
    for (int ks = 0; ks < 4; ++ks) {
      u32x4_t hh;
      hh[0] = cvtpk(x[ks * 2][0], x[ks * 2][1]);
      hh[1] = cvtpk(x[ks * 2][2], x[ks * 2][3]);
      hh[2] = cvtpk(x[ks * 2 + 1][0], x[ks * 2 + 1][1]);
      hh[3] = cvtpk(x[ks * 2 + 1][2], x[ks * 2 + 1][3]);
      a[ks] = __builtin_bit_cast(bf16x8_t, hh);
    }
    // logits for this 16-row tile (hi+lo split, chained per et)
    f32x4_t part = {0.f, 0.f, 0.f, 0.f};
#pragma unroll
    for (int et = 0; et < 8; ++et) {
      f32x4_t v1 = {0.f, 0.f, 0.f, 0.f};
      f32x4_t v2 = v1;
#pragma unroll
      for (int ks = 0; ks < 4; ++ks) {
        const int pidx = ((((et << 2) | ks) << 6) | lane) << 3;
        bf16x8_t bh = *(const bf16x8_t*)(&WPKH[pidx]);
        bf16x8_t bl = *(const bf16x8_t*)(&WPKL[pidx]);
        v1 = __builtin_amdgcn_mfma_f32_16x16x32_bf16(a[ks], bh, v1, 0, 0, 0);
        v2 = __builtin_amdgcn_mfma_f32_16x16x32_bf16(a[ks], bl, v2, 0, 0, 0);
      }
      const float wf = wfreg[et];
#pragma unroll
      for (int i = 0; i < 4; ++i)
        part[i] += wf * fmaxf(v1[i] + v2[i], 0.f);
    }
    // sum over e: butterfly across the 16 lr lanes
#pragma unroll
    for (int m2 = 1; m2 < 16; m2 <<= 1) {
      part[0] += __shfl_xor(part[0], m2, 64);
      part[1] += __shfl_xor(part[1], m2, 64);
      part[2] += __shfl_xor(part[2], m2, 64);
      part[3] += __shfl_xor(part[3], m2, 64);
    }
    // mask rows (lane's own rows: rowb..rowb+3)
    const long rowb = grow + rt * 16 + lg * 4;
    bool mk0, mk1, mk2, mk3;
    if (mode == 0) {
      i32x4_t mv = *(const i32x4_t*)((const int*)maskp + rowb);
      mk0 = mv[0] != 0; mk1 = mv[1] != 0; mk2 = mv[2] != 0; mk3 = mv[3] != 0;
    } else if (mode == 1) {
      unsigned mb = *(const unsigned*)((const unsigned char*)maskp + rowb);
      mk0 = (mb & 255u) != 0; mk1 = ((mb >> 8) & 255u) != 0;
      mk2 = ((mb >> 16) & 255u) != 0; mk3 = (mb >> 24) != 0;
    } else {
      f32x4_t mf = *(const f32x4_t*)((const float*)maskp + rowb);
      mk0 = mf[0] != 0.f; mk1 = mf[1] != 0.f; mk2 = mf[2] != 0.f; mk3 = mf[3] != 0.f;
    }
    part[0] = mk0 ? -1e12f : part[0];
    part[1] = mk1 ? -1e12f : part[1];
    part[2] = mk2 ? -1e12f : part[2];
    part[3] = mk3 ? -1e12f : part[3];
    if (lr == 0) *(f32x4_t*)(&logits[rowb]) = part;   // masked logits (k_attn normalizes)
    // online softmax: wave-shared running max
    float gm = fmaxf(fmaxf(part[0], part[1]), fmaxf(part[2], part[3]));
    gm = fmaxf(gm, __shfl_xor(gm, 16, 64));
    gm = fmaxf(gm, __shfl_xor(gm, 32, 64));
    if (gm > m_run) {
      float sc = expf(m_run - gm);
      s_run *= sc;
#pragma unroll
      for (int k = 0; k < 8; ++k) {
        wacc[k][0] *= sc; wacc[k][1] *= sc; wacc[k][2] *= sc; wacc[k][3] *= sc;
      }
      m_run = gm;
    }
    float pv0 = expf(part[0] - m_run);
    float pv1 = expf(part[1] - m_run);
    float pv2 = expf(part[2] - m_run);
    float pv3 = expf(part[3] - m_run);
    s_run += (pv0 + pv1) + (pv2 + pv3);
    // permute p to ctx-holder lanes: holder (lg2,lr2) needs row lr2 -> src lane (lr2>>2)*16, reg lr2&3
    const int srcl = (lane & 12) << 2;
    float q0 = __shfl(pv0, srcl, 64);
    float q1 = __shfl(pv1, srcl, 64);
    float q2 = __shfl(pv2, srcl, 64);
    float q3 = __shfl(pv3, srcl, 64);
    const int sel = lane & 3;
    float pn = sel == 0 ? q0 : sel == 1 ? q1 : sel == 2 ? q2 : q3;
    // accumulate weighted from exact f32 ctx regs
#pragma unroll
    for (int k = 0; k < 8; ++k) {
      wacc[k][0] += pn * x[k][0]; wacc[k][1] += pn * x[k][1];
      wacc[k][2] += pn * x[k][2]; wacc[k][3] += pn * x[k][3];
    }
  };

#pragma unroll 1
  for (int g = 0; g < 8; ++g) {
    const long grow = rowb0 + (long)g * 32;
    issue(xB, grow, 1);
    process(xA, grow, 0);
    if (g < 7) issue(xA, grow + 32, 0);
    process(xB, grow, 1);
  }

  // ---- wave epilogue: reduce W_acc over the 16 rows (lr bits), s over lg bits ----
#pragma unroll
  for (int m2 = 1; m2 < 16; m2 <<= 1) {
#pragma unroll
    for (int k = 0; k < 8; ++k) {
      wacc[k][0] += __shfl_xor(wacc[k][0], m2, 64);
      wacc[k][1] += __shfl_xor(wacc[k][1], m2, 64);
      wacc[k][2] += __shfl_xor(wacc[k][2], m2, 64);
      wacc[k][3] += __shfl_xor(wacc[k][3], m2, 64);
    }
  }
  float st = s_run;
  st += __shfl_xor(st, 16, 64);
  st += __shfl_xor(st, 32, 64);
  if (lr == 0) {
#pragma unroll
    for (int k = 0; k < 8; ++k) {
      int ks = k >> 1, half = k & 1;
      int col = ks * 32 + lg * 8 + half * 4;
      WB[wave][col + 0] = wacc[k][0];
      WB[wave][col + 1] = wacc[k][1];
      WB[wave][col + 2] = wacc[k][2];
      WB[wave][col + 3] = wacc[k][3];
    }
  }
  if (lane == 0) { MS[wave][0] = m_run; MS[wave][1] = st; }
  __syncthreads();
  // ---- block combine across 8 waves -> per-slice (M, S, W[128]) ----
  if (tid < DD) {
    float M = MS[0][0];
#pragma unroll
    for (int w = 1; w < 8; ++w) M = fmaxf(M, MS[w][0]);
    float Wv = 0.f, S = 0.f;
#pragma unroll
    for (int w = 0; w < 8; ++w) {
      float e = expf(MS[w][0] - M);
      Wv += WB[w][tid] * e;
      S  += MS[w][1] * e;
    }
    Wslice[(long)(b * 4 + slice) * DD + tid] = Wv;
    if (tid == 0) {
      stats[(b * 4 + slice) * 2 + 0] = M;
      stats[(b * 4 + slice) * 2 + 1] = S;
    }
  }
}

// ---- K3: normalize masked logits -> attn. grid (B, 4), 512 thr x 4 elems ----
__global__ void k_attn(float* attnbuf, const float* __restrict__ stats) {
  const int b = blockIdx.x, c = blockIdx.y;
  const int tid = threadIdx.x;               // 512
  float m0 = stats[b * 8 + 0], s0 = stats[b * 8 + 1];
  float m1 = stats[b * 8 + 2], s1 = stats[b * 8 + 3];
  float m2 = stats[b * 8 + 4], s2 = stats[b * 8 + 5];
  float m3 = stats[b * 8 + 6], s3 = stats[b * 8 + 7];
  float M = fmaxf(fmaxf(m0, m1), fmaxf(m2, m3));
  float S = s0 * expf(m0 - M) + s1 * expf(m1 - M) + s2 * expf(m2 - M) + s3 * expf(m3 - M);
  float inv = 1.f / S;
  const long off = (long)b * SS + (long)c * 2048 + (long)tid * 4;
  f32x4_t v = *(const f32x4_t*)(attnbuf + off);
  v[0] = expf(v[0] - M) * inv;
  v[1] = expf(v[1] - M) * inv;
  v[2] = expf(v[2] - M) * inv;
  v[3] = expf(v[3] - M) * inv;
  *(f32x4_t*)(attnbuf + off) = v;
}

// ---- K4: combine slice weighted vectors, h = tanh([weighted,x]@Wout^T). grid(B), 128 thr ----
__global__ void k_final(const float* __restrict__ Wslice, const float* __restrict__ stats,
                        const float* __restrict__ inp, const float* __restrict__ Wout,
                        float* __restrict__ hout) {
  const int b = blockIdx.x;
  const int tid = threadIdx.x;               // 128
  __shared__ float wsh[DD], xin[DD];
  float m0 = stats[b * 8 + 0], s0 = stats[b * 8 + 1];
  float m1 = stats[b * 8 + 2], s1 = stats[b * 8 + 3];
  float m2 = stats[b * 8 + 4], s2 = stats[b * 8 + 5];
  float m3 = stats[b * 8 + 6], s3 = stats[b * 8 + 7];
  float M = fmaxf(fmaxf(m0, m1), fmaxf(m2, m3));
  float e0 = expf(m0 - M), e1 = expf(m1 - M), e2 = expf(m2 - M), e3 = expf(m3 - M);
  float S = s0 * e0 + s1 * e1 + s2 * e2 + s3 * e3;
  float Wv = Wslice[(long)(b * 4 + 0) * DD + tid] * e0
           + Wslice[(long)(b * 4 + 1) * DD + tid] * e1
           + Wslice[(long)(b * 4 + 2) * DD + tid] * e2
           + Wslice[(long)(b * 4 + 3) * DD + tid] * e3;
  wsh[tid] = Wv / S;
  xin[tid] = inp[b * DD + tid];
  __syncthreads();
  const float* wr = Wout + tid * (2 * DD);
  float s = 0.f;
#pragma unroll 8
  for (int f = 0; f < DD; ++f) s += wsh[f] * wr[f];
#pragma unroll 8
  for (int f = 0; f < DD; ++f) s += xin[f] * wr[DD + f];
  hout[b * DD + tid] = tanhf(s);
}

extern "C" void kernel_launch(void* const* d_in, const int* in_sizes, int n_in,
                              void* d_out, int out_size, void* d_ws, size_t ws_size,
                              hipStream_t stream) {
  const float* inp  = (const float*)d_in[0];
  const float* ctx  = (const float*)d_in[1];
  const void*  mask = d_in[2];
  const float* Wg   = (const float*)d_in[3];
  const float* Vg   = (const float*)d_in[4];
  const float* Wout = (const float*)d_in[5];

  float* out = (float*)d_out;
  float* h_out = out;                 // [B, D]
  float* attn_out = out + BB * DD;    // [B, S]  (masked logits -> attn, in place)

  char* ws = (char*)d_ws;
  unsigned int*   flag   = (unsigned int*)ws;
  unsigned short* Whi    = (unsigned short*)(ws + 1024);
  unsigned short* Wlo    = (unsigned short*)(ws + 1024 + 32768);
  float*          wv     = (float*)(ws + 1024 + 65536);
  float*          Wslice = (float*)(ws + 1024 + 65536 + 65536);            // [B][4][D] = 256 KB
  float*          stats  = (float*)(ws + 1024 + 65536 + 65536 + 262144);   // [B][4][2] = 4 KB

  (void)hipMemsetAsync(flag, 0, 4, stream);
  k_detect<<<dim3(256),   dim3(256), 0, stream>>>((const unsigned int*)mask, flag);
  k_prep  <<<dim3(BB),    dim3(DD),  0, stream>>>(inp, Wg, Vg, Whi, Wlo, wv);
  k_logits<<<dim3(4, BB), dim3(512), 0, stream>>>(ctx, Whi, Wlo, wv, mask, flag,
                                                  attn_out, Wslice, stats);
  k_attn  <<<dim3(BB, 4), dim3(512), 0, stream>>>(attn_out, stats);
  k_final <<<dim3(BB),    dim3(128), 0, stream>>>(Wslice, stats, inp, Wout, h_out);
}

// Round 11
// 164.952 us; speedup vs baseline: 1.5390x; 1.0134x over previous
//
#include <hip/hip_runtime.h>

// DeepAttention: h = tanh([attn@ctx, x] @ Wout^T-ish), attn = softmax(mask(w . relu(ctx@W^T)))
// R11: k_logits v6 — flash fusion + 32-row groups sharing B-fragments across 2 row-tiles
// (halves LDS B-traffic, the R10 co-bottleneck). Single xbuf load buffer; PV path
// accumulates from unpacked bf16 A-frags (frees f32 ctx regs, no spill).

#define BB 128
#define SS 8192
#define DD 128

typedef float f32x4_t __attribute__((ext_vector_type(4)));
typedef short bf16x8_t __attribute__((ext_vector_type(8)));
typedef unsigned short u16x8_t __attribute__((ext_vector_type(8)));
typedef unsigned int u32x4_t __attribute__((ext_vector_type(4)));
typedef int i32x4_t __attribute__((ext_vector_type(4)));

__device__ __forceinline__ unsigned short f2bf(float x) {
  unsigned u = __builtin_bit_cast(unsigned, x);
  unsigned r = (u + 0x7FFFu + ((u >> 16) & 1u)) >> 16;
  return (unsigned short)r;
}
__device__ __forceinline__ float bf2f(unsigned short h) {
  unsigned u = ((unsigned)h) << 16;
  return __builtin_bit_cast(float, u);
}
// hw pack: low16 = bf16(a), high16 = bf16(b)  (RNE)
__device__ __forceinline__ unsigned cvtpk(float a, float b) {
  unsigned r;
  asm("v_cvt_pk_bf16_f32 %0, %1, %2" : "=v"(r) : "v"(a), "v"(b));
  return r;
}

// ---- K0: detect mask storage format (0 = int32, 1 = uint8, 2 = float32) ----
__global__ void k_detect(const unsigned int* __restrict__ mw, unsigned int* __restrict__ flag) {
  int i = blockIdx.x * 256 + threadIdx.x;   // 256 blocks -> 65536 words = 256 KB
  unsigned v = mw[i];
  unsigned f = 0;
  if (v == 0x3F800000u) f = 2u;             // f32 1.0 pattern
  else if (v > 1u) f = 1u;                  // packed uint8 bools
  if (f) atomicOr(flag, f);
}

// ---- K1: merged prep. grid(128) x 128 thr.
// (a) W bf16 hi/lo split; (b) w[b,e] = relu(x@W^T)[b,e] * V[e], fp32 exact
__global__ void k_prep(const float* __restrict__ inp, const float* __restrict__ Wg,
                       const float* __restrict__ Vg, unsigned short* __restrict__ Whi,
                       unsigned short* __restrict__ Wlo, float* __restrict__ wv) {
  const int b = blockIdx.x, tid = threadIdx.x;
  {
    int i = b * DD + tid;
    float x = Wg[i];
    unsigned short h = f2bf(x);
    Whi[i] = h;
    Wlo[i] = f2bf(x - bf2f(h));
  }
  __shared__ float xin[DD];
  xin[tid] = inp[b * DD + tid];
  __syncthreads();
  const float* wr = Wg + tid * DD;
  float s = 0.f;
#pragma unroll 8
  for (int d = 0; d < DD; ++d) s += xin[d] * wr[d];
  wv[b * DD + tid] = fmaxf(s, 0.f) * Vg[tid];
}

// ---- K2: fused logits + mask + online-softmax weighted accumulation (v6) ----
// grid (4, BB), 512 thr. Wave: 256 rows = 8 groups of 32 rows (2 row-tiles sharing B-frags).
__launch_bounds__(512, 1)
__global__ void k_logits(const float* __restrict__ ctx, const unsigned short* __restrict__ Whi,
                         const unsigned short* __restrict__ Wlo, const float* __restrict__ wv,
                         const void* __restrict__ maskp, const unsigned int* __restrict__ flag,
                         float* __restrict__ logits, float* __restrict__ Wslice,
                         float* __restrict__ stats) {
  __shared__ unsigned short WPKH[16384];     // 32 KB: W-hi, fragment-packed
  __shared__ unsigned short WPKL[16384];     // 32 KB: W-lo
  __shared__ float wl[DD];
  __shared__ float WB[8][DD];                // 4 KB: per-wave weighted vectors
  __shared__ float MS[8][2];                 // per-wave (m, s)

  const int tid = threadIdx.x;
  const int b = blockIdx.y;
  const int slice = blockIdx.x;              // 0..3, 2048 rows each
  const int wave = tid >> 6;
  const int lane = tid & 63;
  const int lr = lane & 15;
  const int lg = lane >> 4;
  const unsigned mode = *flag;

  const long rowb0 = (long)b * SS + (long)slice * 2048 + (long)wave * 256;

  f32x4_t xbuf[16];                          // 32 rows of ctx (both row-tiles), 64 VGPR
  auto issue = [&](long grow) {
#pragma unroll
    for (int rt = 0; rt < 2; ++rt) {
      const float* rp = ctx + (grow + rt * 16 + lr) * (long)DD + lg * 8;
#pragma unroll
      for (int ks = 0; ks < 4; ++ks) {
        xbuf[rt * 8 + ks * 2]     = *(const f32x4_t*)(rp + ks * 32);
        xbuf[rt * 8 + ks * 2 + 1] = *(const f32x4_t*)(rp + ks * 32 + 4);
      }
    }
  };

  issue(rowb0);                              // group-0 loads fly under W staging

  // Stage W hi/lo into packed-fragment layout. Packed unit p (16B) = frag p>>6, lane p&63.
#pragma unroll
  for (int jj = 0; jj < 4; ++jj) {
    int p = tid + jj * 512;                  // 2048 units per array
    int frag = p >> 6;                       // et*4 + ks
    int li = p & 63;
    int et = frag >> 2, ks = frag & 3;
    int lg2 = li >> 4, lr2 = li & 15;
    int src = (et * 16 + lr2) * DD + ks * 32 + lg2 * 8;
    *(u16x8_t*)(&WPKH[p * 8]) = *(const u16x8_t*)(&Whi[src]);
    *(u16x8_t*)(&WPKL[p * 8]) = *(const u16x8_t*)(&Wlo[src]);
  }
  if (tid < DD) wl[tid] = wv[b * DD + tid];
  __syncthreads();

  float wfreg[8];
#pragma unroll
  for (int et = 0; et < 8; ++et) wfreg[et] = wl[et * 16 + lr];

  float m_run = -3.4e38f, s_run = 0.f;
  f32x4_t wacc[8];
#pragma unroll
  for (int k = 0; k < 8; ++k) wacc[k] = f32x4_t{0.f, 0.f, 0.f, 0.f};

#pragma unroll 1
  for (int g = 0; g < 8; ++g) {
    const long grow = rowb0 + (long)g * 32;
    // ---- convert xbuf -> bf16 A-frags (waits loads; frees xbuf for next issue) ----
    bf16x8_t a[2][4];
#pragma unroll
    for (int rt = 0; rt < 2; ++rt) {
#pragma unroll
      for (int ks = 0; ks < 4; ++ks) {
        f32x4_t x0 = xbuf[rt * 8 + ks * 2];
        f32x4_t x1 = xbuf[rt * 8 + ks * 2 + 1];
        u32x4_t hh;
        hh[0] = cvtpk(x0[0], x0[1]);
        hh[1] = cvtpk(x0[2], x0[3]);
        hh[2] = cvtpk(x1[0], x1[1]);
        hh[3] = cvtpk(x1[2], x1[3]);
        a[rt][ks] = __builtin_bit_cast(bf16x8_t, hh);
      }
    }
    if (g < 7) issue(grow + 32);             // prefetch next group under the MFMAs

    // ---- logits: 8 et-tiles; B-frags read ONCE, applied to both row-tiles ----
    f32x4_t part[2] = {{0.f, 0.f, 0.f, 0.f}, {0.f, 0.f, 0.f, 0.f}};
#pragma unroll
    for (int et = 0; et < 8; ++et) {
      bf16x8_t bh[4], bl[4];
#pragma unroll
      for (int ks = 0; ks < 4; ++ks) {
        const int pidx = ((((et << 2) | ks) << 6) | lane) << 3;
        bh[ks] = *(const bf16x8_t*)(&WPKH[pidx]);
        bl[ks] = *(const bf16x8_t*)(&WPKL[pidx]);
      }
      const float wf = wfreg[et];
#pragma unroll
      for (int rt = 0; rt < 2; ++rt) {
        f32x4_t v1 = {0.f, 0.f, 0.f, 0.f};
        f32x4_t v2 = v1;
#pragma unroll
        for (int ks = 0; ks < 4; ++ks) {
          v1 = __builtin_amdgcn_mfma_f32_16x16x32_bf16(a[rt][ks], bh[ks], v1, 0, 0, 0);
          v2 = __builtin_amdgcn_mfma_f32_16x16x32_bf16(a[rt][ks], bl[ks], v2, 0, 0, 0);
        }
#pragma unroll
        for (int i = 0; i < 4; ++i)
          part[rt][i] += wf * fmaxf(v1[i] + v2[i], 0.f);
      }
    }
    // ---- sum over e: butterfly across the 16 lr lanes ----
#pragma unroll
    for (int rt = 0; rt < 2; ++rt) {
#pragma unroll
      for (int m2 = 1; m2 < 16; m2 <<= 1) {
        part[rt][0] += __shfl_xor(part[rt][0], m2, 64);
        part[rt][1] += __shfl_xor(part[rt][1], m2, 64);
        part[rt][2] += __shfl_xor(part[rt][2], m2, 64);
        part[rt][3] += __shfl_xor(part[rt][3], m2, 64);
      }
    }
    // ---- mask + store masked logits ----
#pragma unroll
    for (int rt = 0; rt < 2; ++rt) {
      const long rowb = grow + rt * 16 + lg * 4;
      bool mk0, mk1, mk2, mk3;
      if (mode == 0) {
        i32x4_t mv = *(const i32x4_t*)((const int*)maskp + rowb);
        mk0 = mv[0] != 0; mk1 = mv[1] != 0; mk2 = mv[2] != 0; mk3 = mv[3] != 0;
      } else if (mode == 1) {
        unsigned mb = *(const unsigned*)((const unsigned char*)maskp + rowb);
        mk0 = (mb & 255u) != 0; mk1 = ((mb >> 8) & 255u) != 0;
        mk2 = ((mb >> 16) & 255u) != 0; mk3 = (mb >> 24) != 0;
      } else {
        f32x4_t mf = *(const f32x4_t*)((const float*)maskp + rowb);
        mk0 = mf[0] != 0.f; mk1 = mf[1] != 0.f; mk2 = mf[2] != 0.f; mk3 = mf[3] != 0.f;
      }
      part[rt][0] = mk0 ? -1e12f : part[rt][0];
      part[rt][1] = mk1 ? -1e12f : part[rt][1];
      part[rt][2] = mk2 ? -1e12f : part[rt][2];
      part[rt][3] = mk3 ? -1e12f : part[rt][3];
      if (lr == 0) *(f32x4_t*)(&logits[rowb]) = part[rt];
    }
    // ---- online softmax update (wave-shared max) ----
    float gm = fmaxf(fmaxf(fmaxf(part[0][0], part[0][1]), fmaxf(part[0][2], part[0][3])),
                     fmaxf(fmaxf(part[1][0], part[1][1]), fmaxf(part[1][2], part[1][3])));
    gm = fmaxf(gm, __shfl_xor(gm, 16, 64));
    gm = fmaxf(gm, __shfl_xor(gm, 32, 64));
    if (gm > m_run) {
      float sc = expf(m_run - gm);
      s_run *= sc;
#pragma unroll
      for (int k = 0; k < 8; ++k) {
        wacc[k][0] *= sc; wacc[k][1] *= sc; wacc[k][2] *= sc; wacc[k][3] *= sc;
      }
      m_run = gm;
    }
    const int srcl = (lane & 12) << 2;
    const int sel = lane & 3;
#pragma unroll
    for (int rt = 0; rt < 2; ++rt) {
      float pv0 = expf(part[rt][0] - m_run);
      float pv1 = expf(part[rt][1] - m_run);
      float pv2 = expf(part[rt][2] - m_run);
      float pv3 = expf(part[rt][3] - m_run);
      s_run += (pv0 + pv1) + (pv2 + pv3);
      // permute p to ctx-holder lanes (holder lr's row = lr; src lane (lr>>2)*16, comp lr&3)
      float q0 = __shfl(pv0, srcl, 64);
      float q1 = __shfl(pv1, srcl, 64);
      float q2 = __shfl(pv2, srcl, 64);
      float q3 = __shfl(pv3, srcl, 64);
      float pn = sel == 0 ? q0 : sel == 1 ? q1 : sel == 2 ? q2 : q3;
      // accumulate weighted from unpacked bf16 A-frags (d = ks*32+lg*8 + elem)
#pragma unroll
      for (int ks = 0; ks < 4; ++ks) {
        u32x4_t u = __builtin_bit_cast(u32x4_t, a[rt][ks]);
#pragma unroll
        for (int j = 0; j < 4; ++j) {
          float flo = __builtin_bit_cast(float, u[j] << 16);
          float fhi = __builtin_bit_cast(float, u[j] & 0xFFFF0000u);
          wacc[ks * 2 + (j >> 1)][(j & 1) * 2 + 0] += pn * flo;
          wacc[ks * 2 + (j >> 1)][(j & 1) * 2 + 1] += pn * fhi;
        }
      }
    }
  }

  // ---- wave epilogue: reduce W_acc over the 16 rows (lr bits), s over lg bits ----
#pragma unroll
  for (int m2 = 1; m2 < 16; m2 <<= 1) {
#pragma unroll
    for (int k = 0; k < 8; ++k) {
      wacc[k][0] += __shfl_xor(wacc[k][0], m2, 64);
      wacc[k][1] += __shfl_xor(wacc[k][1], m2, 64);
      wacc[k][2] += __shfl_xor(wacc[k][2], m2, 64);
      wacc[k][3] += __shfl_xor(wacc[k][3], m2, 64);
    }
  }
  float st = s_run;
  st += __shfl_xor(st, 16, 64);
  st += __shfl_xor(st, 32, 64);
  if (lr == 0) {
#pragma unroll
    for (int k = 0; k < 8; ++k) {
      int ks = k >> 1, half = k & 1;
      int col = ks * 32 + lg * 8 + half * 4;
      WB[wave][col + 0] = wacc[k][0];
      WB[wave][col + 1] = wacc[k][1];
      WB[wave][col + 2] = wacc[k][2];
      WB[wave][col + 3] = wacc[k][3];
    }
  }
  if (lane == 0) { MS[wave][0] = m_run; MS[wave][1] = st; }
  __syncthreads();
  // ---- block combine across 8 waves -> per-slice (M, S, W[128]) ----
  if (tid < DD) {
    float M = MS[0][0];
#pragma unroll
    for (int w = 1; w < 8; ++w) M = fmaxf(M, MS[w][0]);
    float Wv = 0.f, S = 0.f;
#pragma unroll
    for (int w = 0; w < 8; ++w) {
      float e = expf(MS[w][0] - M);
      Wv += WB[w][tid] * e;
      S  += MS[w][1] * e;
    }
    Wslice[(long)(b * 4 + slice) * DD + tid] = Wv;
    if (tid == 0) {
      stats[(b * 4 + slice) * 2 + 0] = M;
      stats[(b * 4 + slice) * 2 + 1] = S;
    }
  }
}

// ---- K3: normalize masked logits -> attn. grid (B, 4), 512 thr x 4 elems ----
__global__ void k_attn(float* attnbuf, const float* __restrict__ stats) {
  const int b = blockIdx.x, c = blockIdx.y;
  const int tid = threadIdx.x;               // 512
  float m0 = stats[b * 8 + 0], s0 = stats[b * 8 + 1];
  float m1 = stats[b * 8 + 2], s1 = stats[b * 8 + 3];
  float m2 = stats[b * 8 + 4], s2 = stats[b * 8 + 5];
  float m3 = stats[b * 8 + 6], s3 = stats[b * 8 + 7];
  float M = fmaxf(fmaxf(m0, m1), fmaxf(m2, m3));
  float S = s0 * expf(m0 - M) + s1 * expf(m1 - M) + s2 * expf(m2 - M) + s3 * expf(m3 - M);
  float inv = 1.f / S;
  const long off = (long)b * SS + (long)c * 2048 + (long)tid * 4;
  f32x4_t v = *(const f32x4_t*)(attnbuf + off);
  v[0] = expf(v[0] - M) * inv;
  v[1] = expf(v[1] - M) * inv;
  v[2] = expf(v[2] - M) * inv;
  v[3] = expf(v[3] - M) * inv;
  *(f32x4_t*)(attnbuf + off) = v;
}

// ---- K4: combine slice weighted vectors, h = tanh([weighted,x]@Wout^T). grid(B), 128 thr ----
__global__ void k_final(const float* __restrict__ Wslice, const float* __restrict__ stats,
                        const float* __restrict__ inp, const float* __restrict__ Wout,
                        float* __restrict__ hout) {
  const int b = blockIdx.x;
  const int tid = threadIdx.x;               // 128
  __shared__ float wsh[DD], xin[DD];
  float m0 = stats[b * 8 + 0], s0 = stats[b * 8 + 1];
  float m1 = stats[b * 8 + 2], s1 = stats[b * 8 + 3];
  float m2 = stats[b * 8 + 4], s2 = stats[b * 8 + 5];
  float m3 = stats[b * 8 + 6], s3 = stats[b * 8 + 7];
  float M = fmaxf(fmaxf(m0, m1), fmaxf(m2, m3));
  float e0 = expf(m0 - M), e1 = expf(m1 - M), e2 = expf(m2 - M), e3 = expf(m3 - M);
  float S = s0 * e0 + s1 * e1 + s2 * e2 + s3 * e3;
  float Wv = Wslice[(long)(b * 4 + 0) * DD + tid] * e0
           + Wslice[(long)(b * 4 + 1) * DD + tid] * e1
           + Wslice[(long)(b * 4 + 2) * DD + tid] * e2
           + Wslice[(long)(b * 4 + 3) * DD + tid] * e3;
  wsh[tid] = Wv / S;
  xin[tid] = inp[b * DD + tid];
  __syncthreads();
  const float* wr = Wout + tid * (2 * DD);
  float s = 0.f;
#pragma unroll 8
  for (int f = 0; f < DD; ++f) s += wsh[f] * wr[f];
#pragma unroll 8
  for (int f = 0; f < DD; ++f) s += xin[f] * wr[DD + f];
  hout[b * DD + tid] = tanhf(s);
}

extern "C" void kernel_launch(void* const* d_in, const int* in_sizes, int n_in,
                              void* d_out, int out_size, void* d_ws, size_t ws_size,
                              hipStream_t stream) {
  const float* inp  = (const float*)d_in[0];
  const float* ctx  = (const float*)d_in[1];
  const void*  mask = d_in[2];
  const float* Wg   = (const float*)d_in[3];
  const float* Vg   = (const float*)d_in[4];
  const float* Wout = (const float*)d_in[5];

  float* out = (float*)d_out;
  float* h_out = out;                 // [B, D]
  float* attn_out = out + BB * DD;    // [B, S]  (masked logits -> attn, in place)

  char* ws = (char*)d_ws;
  unsigned int*   flag   = (unsigned int*)ws;
  unsigned short* Whi    = (unsigned short*)(ws + 1024);
  unsigned short* Wlo    = (unsigned short*)(ws + 1024 + 32768);
  float*          wv     = (float*)(ws + 1024 + 65536);
  float*          Wslice = (float*)(ws + 1024 + 65536 + 65536);            // [B][4][D] = 256 KB
  float*          stats  = (float*)(ws + 1024 + 65536 + 65536 + 262144);   // [B][4][2] = 4 KB

  (void)hipMemsetAsync(flag, 0, 4, stream);
  k_detect<<<dim3(256),   dim3(256), 0, stream>>>((const unsigned int*)mask, flag);
  k_prep  <<<dim3(BB),    dim3(DD),  0, stream>>>(inp, Wg, Vg, Whi, Wlo, wv);
  k_logits<<<dim3(4, BB), dim3(512), 0, stream>>>(ctx, Whi, Wlo, wv, mask, flag,
                                                  attn_out, Wslice, stats);
  k_attn  <<<dim3(BB, 4), dim3(512), 0, stream>>>(attn_out, stats);
  k_final <<<dim3(BB),    dim3(128), 0, stream>>>(Wslice, stats, inp, Wout, h_out);
}